// Round 6
// baseline (174.902 us; speedup 1.0000x reference)
//
#include <hip/hip_runtime.h>
#include <hip/hip_bf16.h>

// y = (spikes @ V) @ U^T
// spikes: [4096, 16384] f32, V: [16384, 32] f32, U: [16384, 32] f32
// y: [4096, 16384] f32 (268 MB). Mask inputs are dead in the reference.
//
// Phase A: bf16 MFMA 16x16x32, K-split NC ways. A staged via dense coalesced
// global_load_lds (1 KB/instr) into double-buffered LDS tiles; fragment reads
// use a 32B-pair XOR swizzle realized by PRE-SWIZZLING the global source
// (DMA dest must stay linear). V pre-packed to bf16 B-fragment order (1 MB).

#define B_DIM 4096
#define NPRE  16384
#define NPOST 16384
#define RDIM  32

#define NC     16
#define CHUNK  (NPRE / NC)       // 1024 k per block
#define TILEK  64                // k per LDS tile
#define NTILE  (CHUNK / TILEK)   // 16 tiles
#define ROWS_A 64                // rows per block
#define TILEF  (ROWS_A * TILEK)  // 4096 floats = 16 KB per buffer

typedef __attribute__((ext_vector_type(8))) short short8;   // 8 bf16 = 4 VGPRs
typedef __attribute__((ext_vector_type(4))) float f32x4;

typedef const __attribute__((address_space(1))) void GAS;
typedef __attribute__((address_space(3))) void LAS;

static __device__ __forceinline__ unsigned pack_bf2(float lo, float hi) {
    union { __hip_bfloat162 h; unsigned u; } c;
    c.h = __float22bfloat162_rn(make_float2(lo, hi));   // v_cvt_pk_bf16_f32
    return c.u;
}

// ---- V packing (unchanged, proven): vpack[((ktg*2+half)*64+lane)*8 + e]
//      = bf16(V[ktg*32 + (lane>>4)*8 + e][half*16 + (lane&15)])
__global__ void vpack_kernel(const float* __restrict__ V, short* __restrict__ vpack)
{
    const int tid  = blockIdx.x * 256 + threadIdx.x;   // 65536
    const int lane = tid & 63;
    const int half = (tid >> 6) & 1;
    const int ktg  = tid >> 7;
    const int n    = half * 16 + (lane & 15);
    const int k0   = ktg * 32 + (lane >> 4) * 8;
    union { short8 s; short el[8]; } f;
    #pragma unroll
    for (int e = 0; e < 8; ++e) {
        union { __hip_bfloat16 h; short s; } c;
        c.h = __float2bfloat16(V[(size_t)(k0 + e) * RDIM + n]);
        f.el[e] = c.s;
    }
    *reinterpret_cast<short8*>(vpack + (size_t)tid * 8) = f.s;
}

// ---- phase A: block = (kc, 64-row strip); wave w owns rows w*16..w*16+15 ---
__global__ __launch_bounds__(256) void zpart_kernel(
    const float* __restrict__ spikes, const short* __restrict__ vpack,
    float* __restrict__ part)
{
    __shared__ float smem[2 * TILEF];   // 32 KB

    const int tid  = threadIdx.x;
    const int lane = tid & 63;
    const int w    = tid >> 6;                 // wave 0..3
    const int kc   = blockIdx.x;               // k-chunk
    const int brow = blockIdx.y * ROWS_A;

    // --- staging descriptors: wave w issues insts i = w*4+q, each 1 KB (4 rows)
    // lds linear: byte i*1024 + lane*16 -> row lr = i*4+(lane>>4), granule g=lane&15.
    // stored granule g holds ORIGINAL pair (g>>1)^(lr&7), elem (g&1)  (32B-pair XOR)
    const float* gsrc[4];
    int ldst[4];
    #pragma unroll
    for (int q = 0; q < 4; ++q) {
        const int i  = w * 4 + q;
        const int lr = i * 4 + (lane >> 4);
        const int g  = lane & 15;
        const int sg = ((((g >> 1) ^ (lr & 7)) << 1) | (g & 1));   // source granule
        gsrc[q] = spikes + (size_t)(brow + lr) * NPRE + (size_t)kc * CHUNK + sg * 4;
        ldst[q] = i * 1024;                    // wave-uniform byte base (HW adds lane*16)
    }

    // --- consume descriptors
    const int m  = lane & 15;                  // fragment row within strip
    const int kg = lane >> 4;                  // k-group
    const int lr = w * 16 + m;                 // row within 64-row tile
    const short* bb = vpack + ((size_t)kc * 32) * 1024 + lane * 8;

    f32x4 acc0 = {0.f, 0.f, 0.f, 0.f};
    f32x4 acc1 = {0.f, 0.f, 0.f, 0.f};

    // prologue: stage tile 0 -> buf 0
    #pragma unroll
    for (int q = 0; q < 4; ++q)
        __builtin_amdgcn_global_load_lds((GAS*)gsrc[q],
            (LAS*)((char*)smem + ldst[q]), 16, 0, 0);

    int cur = 0;
    #pragma unroll 1
    for (int t = 0; t < NTILE; ++t) {
        __syncthreads();                       // tile t resident in buf cur

        if (t + 1 < NTILE) {                   // DMA tile t+1 -> other buf (flies under compute)
            const int nb = cur ^ 1;
            #pragma unroll
            for (int q = 0; q < 4; ++q)
                __builtin_amdgcn_global_load_lds((GAS*)(gsrc[q] + (size_t)(t + 1) * TILEK),
                    (LAS*)((char*)smem + nb * (TILEF * 4) + ldst[q]), 16, 0, 0);
        }

        // B fragments for both k-steps of this tile (L1/L2-resident stream)
        const short* bt = bb + (size_t)t * 2048;
        short8 b00 = *reinterpret_cast<const short8*>(bt);
        short8 b01 = *reinterpret_cast<const short8*>(bt + 512);
        short8 b10 = *reinterpret_cast<const short8*>(bt + 1024);
        short8 b11 = *reinterpret_cast<const short8*>(bt + 1536);

        const char* sb = (const char*)smem + cur * (TILEF * 4) + lr * 256;

        // k-step s=0
        {
            const int pp = (0 * 4 + kg) ^ (lr & 7);
            const f32x4 al = *reinterpret_cast<const f32x4*>(sb + pp * 32);
            const f32x4 ah = *reinterpret_cast<const f32x4*>(sb + pp * 32 + 16);
            union { short8 s; unsigned u[4]; } af;
            af.u[0] = pack_bf2(al.x, al.y);
            af.u[1] = pack_bf2(al.z, al.w);
            af.u[2] = pack_bf2(ah.x, ah.y);
            af.u[3] = pack_bf2(ah.z, ah.w);
            acc0 = __builtin_amdgcn_mfma_f32_16x16x32_bf16(af.s, b00, acc0, 0, 0, 0);
            acc1 = __builtin_amdgcn_mfma_f32_16x16x32_bf16(af.s, b01, acc1, 0, 0, 0);
        }
        // k-step s=1
        {
            const int pp = (1 * 4 + kg) ^ (lr & 7);
            const f32x4 al = *reinterpret_cast<const f32x4*>(sb + pp * 32);
            const f32x4 ah = *reinterpret_cast<const f32x4*>(sb + pp * 32 + 16);
            union { short8 s; unsigned u[4]; } af;
            af.u[0] = pack_bf2(al.x, al.y);
            af.u[1] = pack_bf2(al.z, al.w);
            af.u[2] = pack_bf2(ah.x, ah.y);
            af.u[3] = pack_bf2(ah.z, ah.w);
            acc0 = __builtin_amdgcn_mfma_f32_16x16x32_bf16(af.s, b10, acc0, 0, 0, 0);
            acc1 = __builtin_amdgcn_mfma_f32_16x16x32_bf16(af.s, b11, acc1, 0, 0, 0);
        }

        cur ^= 1;
    }

    // C layout: n = lane&15, out-row = kg*4 + j within the wave's 16-row strip
    float* pout = part + ((size_t)kc * B_DIM + brow + w * 16) * RDIM;
    #pragma unroll
    for (int j = 0; j < 4; ++j) {
        const int ro = (kg * 4 + j) * RDIM;
        pout[ro + m]      = acc0[j];
        pout[ro + 16 + m] = acc1[j];
    }
}

// ---- z reduction: z[b][r] = sum_c part[c][b][r] ---------------------------
__global__ void zreduce_kernel(const float* __restrict__ part, float* __restrict__ z)
{
    const int idx = (blockIdx.x * blockDim.x + threadIdx.x) * 4;  // 131072 floats
    float sx = 0.f, sy = 0.f, sz = 0.f, sw = 0.f;
    #pragma unroll
    for (int c = 0; c < NC; ++c) {
        const float4 p = *reinterpret_cast<const float4*>(
            &part[(size_t)c * (B_DIM * RDIM) + idx]);
        sx += p.x; sy += p.y; sz += p.z; sw += p.w;
    }
    float4 s4; s4.x = sx; s4.y = sy; s4.z = sz; s4.w = sw;
    *reinterpret_cast<float4*>(&z[idx]) = s4;
}

// ---- phase B: y[b][j] = sum_r z[b][r] * U[j][r] ---------------------------
#define TJ 256
#define TB 64

__global__ __launch_bounds__(256) void ykernel(
    const float* __restrict__ z, const float* __restrict__ U,
    float* __restrict__ y)
{
    const int j  = blockIdx.x * TJ + threadIdx.x;
    const int b0 = blockIdx.y * TB;

    float u[RDIM];
    #pragma unroll
    for (int q = 0; q < 8; ++q) {
        const float4 v = *reinterpret_cast<const float4*>(&U[(size_t)j * RDIM + q * 4]);
        u[q * 4 + 0] = v.x; u[q * 4 + 1] = v.y; u[q * 4 + 2] = v.z; u[q * 4 + 3] = v.w;
    }

    for (int bb = 0; bb < TB; ++bb) {
        const float* zr = &z[(size_t)(b0 + bb) * RDIM];
        float a0 = 0.f, a1 = 0.f, a2 = 0.f, a3 = 0.f;
        #pragma unroll
        for (int r = 0; r < RDIM; r += 4) {
            a0 += zr[r + 0] * u[r + 0];
            a1 += zr[r + 1] * u[r + 1];
            a2 += zr[r + 2] * u[r + 2];
            a3 += zr[r + 3] * u[r + 3];
        }
        y[(size_t)(b0 + bb) * NPOST + j] = (a0 + a1) + (a2 + a3);
    }
}

extern "C" void kernel_launch(void* const* d_in, const int* in_sizes, int n_in,
                              void* d_out, int out_size, void* d_ws, size_t ws_size,
                              hipStream_t stream)
{
    const float* spikes = (const float*)d_in[0];   // [4096, 16384]
    const float* U      = (const float*)d_in[1];   // [16384, 32]
    const float* V      = (const float*)d_in[2];   // [16384, 32]

    float* y     = (float*)d_out;
    float* part  = (float*)d_out;                         // [16][4096][32] f32 = 8 MB
    short* vpack = (short*)((float*)d_out + (size_t)NC * B_DIM * RDIM);  // 1 MB after partials
    float* z     = (float*)d_ws;                          // 512 KB

    vpack_kernel<<<256, 256, 0, stream>>>(V, vpack);
    zpart_kernel<<<dim3(NC, B_DIM / ROWS_A), 256, 0, stream>>>(spikes, vpack, part);
    zreduce_kernel<<<dim3((B_DIM * RDIM / 4) / 256), 256, 0, stream>>>(part, z);
    ykernel<<<dim3(NPOST / TJ, B_DIM / TB), 256, 0, stream>>>(z, U, y);
}